// Round 1
// baseline (1486.315 us; speedup 1.0000x reference)
//
#include <hip/hip_runtime.h>
#include <math.h>

#define TEMPERATURE 0.07f

// ---------------- ws layout (float offsets) ----------------
#define WS_COST   0          // 128*128*128 = 2097152
#define WS_SIM    2097152    // 16384
#define WS_IVG    2113536    // 128
#define WS_ITG    2113664    // 128
#define WS_IVV    2113792    // 16384
#define WS_IVT    2130176    // 16384
#define WS_COLS   2146560    // 16384 ints
#define WS_ACC    2162944    // 16 floats

// ---------------- init: zero accumulators ----------------
__global__ void k_init(float* acc) {
    if (threadIdx.x < 16) acc[threadIdx.x] = 0.0f;
}

// ---------------- row inverse norms: x [rows][1024] ----------------
__global__ __launch_bounds__(256) void k_invnorm(const float* __restrict__ x,
                                                 float* __restrict__ out, int rows) {
    int wid = threadIdx.x >> 6;
    int lane = threadIdx.x & 63;
    int row = blockIdx.x * 4 + wid;
    if (row >= rows) return;
    const float* xr = x + (size_t)row * 1024;
    float s = 0.0f;
#pragma unroll
    for (int i = 0; i < 4; i++) {
        float4 v = *(const float4*)&xr[i * 256 + lane * 4];
        s += v.x * v.x + v.y * v.y + v.z * v.z + v.w * v.w;
    }
#pragma unroll
    for (int off = 32; off > 0; off >>= 1) s += __shfl_xor(s, off);
    if (lane == 0) out[row] = 1.0f / fmaxf(sqrtf(s), 1e-12f);
}

// ---------------- sim[i][j] = dot(v_g[i], t_g[j]) * iv[i]*it[j] / TEMP ----------------
__global__ __launch_bounds__(128) void k_sim(const float* __restrict__ vg,
                                             const float* __restrict__ tg,
                                             const float* __restrict__ ivg,
                                             const float* __restrict__ itg,
                                             float* __restrict__ sim) {
    int i = blockIdx.x, j = threadIdx.x;
    const float* vr = vg + (size_t)i * 1024;
    const float* tr = tg + (size_t)j * 1024;
    float acc = 0.0f;
    for (int k = 0; k < 1024; k += 4) {
        float4 a = *(const float4*)&vr[k];
        float4 b = *(const float4*)&tr[k];
        acc += a.x * b.x + a.y * b.y + a.z * b.z + a.w * b.w;
    }
    sim[i * 128 + j] = acc * ivg[i] * itg[j] / TEMPERATURE;
}

// ---------------- L_global from sim (single block, 128 threads) ----------------
__global__ __launch_bounds__(128) void k_global(const float* __restrict__ sim,
                                                float* __restrict__ acc) {
    __shared__ float red[128];
    int t = threadIdx.x;
    float m = -3e38f, m2 = -3e38f;
    for (int j = 0; j < 128; j++) {
        m = fmaxf(m, sim[t * 128 + j]);
        m2 = fmaxf(m2, sim[j * 128 + t]);
    }
    float s = 0.0f, s2 = 0.0f;
    for (int j = 0; j < 128; j++) {
        s += expf(sim[t * 128 + j] - m);
        s2 += expf(sim[j * 128 + t] - m2);
    }
    float contrib = 2.0f * sim[t * 128 + t] - (m + logf(s)) - (m2 + logf(s2));
    red[t] = contrib;
    __syncthreads();
    for (int o = 64; o > 0; o >>= 1) {
        if (t < o) red[t] += red[t + o];
        __syncthreads();
    }
    if (t == 0) acc[0] = -red[0] / 256.0f;   // 0.5*(mean+mean), negated
}

// ---------------- cost[b][n][m] = 1 - cos(V[b,n], T[b,m]) ----------------
// 64x64 output tile per block, 4x4 register tile per thread, K-chunks of 16 in LDS.
__global__ __launch_bounds__(256) void k_cost(const float* __restrict__ V,
                                              const float* __restrict__ T,
                                              const float* __restrict__ ivv,
                                              const float* __restrict__ ivt,
                                              float* __restrict__ cost) {
    __shared__ float As[16][68];  // [k][row], padded to 68 (16B-aligned rows, bank-spread)
    __shared__ float Bs[16][68];
    int b = blockIdx.x >> 2;
    int tile = blockIdx.x & 3;
    int n0 = (tile >> 1) * 64, m0 = (tile & 1) * 64;
    int t = threadIdx.x;
    int lr = t >> 2;   // 0..63 (tile row)
    int lq = t & 3;    // 0..3  (k quarter)
    int tm = t >> 4;   // 0..15
    int tn = t & 15;   // 0..15
    const float* Vb = V + (size_t)b * 128 * 1024;
    const float* Tb = T + (size_t)b * 128 * 1024;
    float acc[4][4];
#pragma unroll
    for (int i = 0; i < 4; i++)
#pragma unroll
        for (int j = 0; j < 4; j++) acc[i][j] = 0.0f;

    for (int k0 = 0; k0 < 1024; k0 += 16) {
        float4 av = *(const float4*)&Vb[(size_t)(n0 + lr) * 1024 + k0 + lq * 4];
        float4 bv = *(const float4*)&Tb[(size_t)(m0 + lr) * 1024 + k0 + lq * 4];
        __syncthreads();
        As[lq * 4 + 0][lr] = av.x; As[lq * 4 + 1][lr] = av.y;
        As[lq * 4 + 2][lr] = av.z; As[lq * 4 + 3][lr] = av.w;
        Bs[lq * 4 + 0][lr] = bv.x; Bs[lq * 4 + 1][lr] = bv.y;
        Bs[lq * 4 + 2][lr] = bv.z; Bs[lq * 4 + 3][lr] = bv.w;
        __syncthreads();
#pragma unroll
        for (int k = 0; k < 16; k++) {
            float4 a = *(const float4*)&As[k][tm * 4];
            float4 q = *(const float4*)&Bs[k][tn * 4];
            acc[0][0] += a.x * q.x; acc[0][1] += a.x * q.y; acc[0][2] += a.x * q.z; acc[0][3] += a.x * q.w;
            acc[1][0] += a.y * q.x; acc[1][1] += a.y * q.y; acc[1][2] += a.y * q.z; acc[1][3] += a.y * q.w;
            acc[2][0] += a.z * q.x; acc[2][1] += a.z * q.y; acc[2][2] += a.z * q.z; acc[2][3] += a.z * q.w;
            acc[3][0] += a.w * q.x; acc[3][1] += a.w * q.y; acc[3][2] += a.w * q.z; acc[3][3] += a.w * q.w;
        }
    }
    int nb = n0 + tm * 4, mb = m0 + tn * 4;
    float im[4];
#pragma unroll
    for (int j = 0; j < 4; j++) im[j] = ivt[b * 128 + mb + j];
#pragma unroll
    for (int i = 0; i < 4; i++) {
        float in_ = ivv[b * 128 + nb + i];
        float4 o;
        o.x = 1.0f - acc[i][0] * in_ * im[0];
        o.y = 1.0f - acc[i][1] * in_ * im[1];
        o.z = 1.0f - acc[i][2] * in_ * im[2];
        o.w = 1.0f - acc[i][3] * in_ * im[3];
        *(float4*)&cost[((size_t)b * 128 + nb + i) * 128 + mb] = o;
    }
}

// ---------------- Hungarian (JV) — one wave per batch problem ----------------
// Lane l owns columns l and l+64, and rows l and l+64. All JV state in registers;
// cost matrix in LDS; wave-uniform control flow; argmin via shfl_xor butterfly.
__global__ __launch_bounds__(64) void k_hungarian(const float* __restrict__ cost,
                                                  int* __restrict__ cols) {
    extern __shared__ float C[];  // 128*128 floats = 64 KB
    int b = blockIdx.x;
    int lane = threadIdx.x;
    for (int i = lane * 4; i < 16384; i += 256)
        *(float4*)&C[i] = *(const float4*)&cost[(size_t)b * 16384 + i];
    __syncthreads();

    const float INF = 3.0e38f;
    float v0 = 0.0f, v1 = 0.0f, u0 = 0.0f, u1 = 0.0f;
    int p0 = -1, p1 = -1;

    for (int i = 0; i < 128; i++) {
        float minv0 = INF, minv1 = INF;
        int way0 = 128, way1 = 128;
        bool used0 = false, used1 = false, intree0 = false, intree1 = false;
        if (lane == (i & 63)) { if (i < 64) intree0 = true; else intree1 = true; }
        int j0 = 128;  // virtual column
        int guard = 0;
        while (true) {
            int i0;
            if (j0 == 128) {
                i0 = i;
            } else {
                int jl = j0 & 63;
                int pv = __shfl((j0 >= 64) ? p1 : p0, jl);
                i0 = pv;
                if (lane == jl) { if (j0 >= 64) used1 = true; else used0 = true; }
                if (lane == (i0 & 63)) { if (i0 < 64) intree0 = true; else intree1 = true; }
            }
            float ui0 = __shfl((i0 >= 64) ? u1 : u0, i0 & 63);
            float c0 = C[i0 * 128 + lane];
            float c1 = C[i0 * 128 + 64 + lane];
            float cur0 = c0 - ui0 - v0;
            float cur1 = c1 - ui0 - v1;
            if (!used0 && cur0 < minv0) { minv0 = cur0; way0 = j0; }
            if (!used1 && cur1 < minv1) { minv1 = cur1; way1 = j0; }
            float cand0 = used0 ? INF : minv0;
            float cand1 = used1 ? INF : minv1;
            float bv; int bi;
            if (cand0 <= cand1) { bv = cand0; bi = lane; }
            else                { bv = cand1; bi = lane + 64; }
#pragma unroll
            for (int off = 32; off > 0; off >>= 1) {
                float ov = __shfl_xor(bv, off);
                int oi = __shfl_xor(bi, off);
                if (ov < bv || (ov == bv && oi < bi)) { bv = ov; bi = oi; }
            }
            float delta = bv;
            int j1 = bi;
            if (used0) v0 -= delta; else minv0 -= delta;
            if (used1) v1 -= delta; else minv1 -= delta;
            if (intree0) u0 += delta;
            if (intree1) u1 += delta;
            j0 = j1;
            int pj = __shfl((j0 >= 64) ? p1 : p0, j0 & 63);
            if (pj < 0 || ++guard > 200) break;
        }
        // augment along alternating path
        while (j0 != 128) {
            int w = __shfl((j0 >= 64) ? way1 : way0, j0 & 63);
            int pw = (w == 128) ? i : __shfl((w >= 64) ? p1 : p0, w & 63);
            if (lane == (j0 & 63)) { if (j0 >= 64) p1 = pw; else p0 = pw; }
            j0 = w;
        }
    }
    // p[j] = row matched to column j  ->  cols[row] = j
    cols[b * 128 + p0] = lane;
    cols[b * 128 + p1] = lane + 64;
}

// ---------------- node MSE: one block per (b,n) row ----------------
__global__ __launch_bounds__(256) void k_node(const float* __restrict__ V,
                                              const float* __restrict__ T,
                                              const int* __restrict__ cols,
                                              float* __restrict__ acc) {
    int bn = blockIdx.x;
    int b = bn >> 7, n = bn & 127;
    int c = cols[bn];
    const float* vr = V + ((size_t)b * 128 + n) * 1024;
    const float* tr = T + ((size_t)b * 128 + c) * 1024;
    int t = threadIdx.x;
    float4 a = *(const float4*)&vr[t * 4];
    float4 bb = *(const float4*)&tr[t * 4];
    float dx = a.x - bb.x, dy = a.y - bb.y, dz = a.z - bb.z, dw = a.w - bb.w;
    float s = dx * dx + dy * dy + dz * dz + dw * dw;
#pragma unroll
    for (int off = 32; off > 0; off >>= 1) s += __shfl_xor(s, off);
    __shared__ float wsum[4];
    if ((t & 63) == 0) wsum[t >> 6] = s;
    __syncthreads();
    if (t == 0) atomicAdd(&acc[1], wsum[0] + wsum[1] + wsum[2] + wsum[3]);
}

// ---------------- graph MSE ----------------
__global__ __launch_bounds__(256) void k_graph(const float* __restrict__ Av,
                                               const float* __restrict__ At,
                                               float* __restrict__ acc) {
    size_t idx = ((size_t)blockIdx.x * 256 + threadIdx.x) * 4;
    float4 a = *(const float4*)&Av[idx];
    float4 bb = *(const float4*)&At[idx];
    float dx = a.x - bb.x, dy = a.y - bb.y, dz = a.z - bb.z, dw = a.w - bb.w;
    float s = dx * dx + dy * dy + dz * dz + dw * dw;
#pragma unroll
    for (int off = 32; off > 0; off >>= 1) s += __shfl_xor(s, off);
    __shared__ float wsum[4];
    int t = threadIdx.x;
    if ((t & 63) == 0) wsum[t >> 6] = s;
    __syncthreads();
    if (t == 0) atomicAdd(&acc[2], wsum[0] + wsum[1] + wsum[2] + wsum[3]);
}

// ---------------- finalize ----------------
__global__ void k_final(const float* __restrict__ acc, float* __restrict__ out) {
    float lg = acc[0];
    float ln = acc[1] / 16777216.0f;   // 128*128*1024
    float lgr = acc[2] / 2097152.0f;   // 128*128*128
    out[0] = lg + ln + lgr;
    out[1] = lg;
    out[2] = ln;
    out[3] = lgr;
}

extern "C" void kernel_launch(void* const* d_in, const int* in_sizes, int n_in,
                              void* d_out, int out_size, void* d_ws, size_t ws_size,
                              hipStream_t stream) {
    const float* vg = (const float*)d_in[0];
    const float* tg = (const float*)d_in[1];
    const float* V  = (const float*)d_in[2];
    const float* T  = (const float*)d_in[3];
    const float* Av = (const float*)d_in[4];
    const float* At = (const float*)d_in[5];
    float* out = (float*)d_out;
    float* ws = (float*)d_ws;

    float* cost = ws + WS_COST;
    float* sim  = ws + WS_SIM;
    float* ivg  = ws + WS_IVG;
    float* itg  = ws + WS_ITG;
    float* ivv  = ws + WS_IVV;
    float* ivt  = ws + WS_IVT;
    int*   cols = (int*)(ws + WS_COLS);
    float* acc  = ws + WS_ACC;

    k_init<<<1, 16, 0, stream>>>(acc);

    k_invnorm<<<32, 256, 0, stream>>>(vg, ivg, 128);
    k_invnorm<<<32, 256, 0, stream>>>(tg, itg, 128);
    k_invnorm<<<4096, 256, 0, stream>>>(V, ivv, 16384);
    k_invnorm<<<4096, 256, 0, stream>>>(T, ivt, 16384);

    k_sim<<<128, 128, 0, stream>>>(vg, tg, ivg, itg, sim);
    k_global<<<1, 128, 0, stream>>>(sim, acc);

    k_cost<<<512, 256, 0, stream>>>(V, T, ivv, ivt, cost);
    k_hungarian<<<128, 64, 65536, stream>>>(cost, cols);

    k_node<<<16384, 256, 0, stream>>>(V, T, cols, acc);
    k_graph<<<2048, 256, 0, stream>>>(Av, At, acc);

    k_final<<<1, 1, 0, stream>>>(acc, out);
}

// Round 2
// 910.074 us; speedup vs baseline: 1.6332x; 1.6332x over previous
//
#include <hip/hip_runtime.h>
#include <math.h>

#define TEMPERATURE 0.07f

// ---------------- ws layout (float offsets) ----------------
#define WS_COST   0          // 128*128*128 = 2097152
#define WS_SIM    2097152    // 16384
#define WS_IVG    2113536    // 128
#define WS_ITG    2113664    // 128
#define WS_IVV    2113792    // 16384
#define WS_IVT    2130176    // 16384
#define WS_COLS   2146560    // 16384 ints
#define WS_ACC    2162944    // 16 floats

// ---------------- init: zero accumulators ----------------
__global__ void k_init(float* acc) {
    if (threadIdx.x < 16) acc[threadIdx.x] = 0.0f;
}

// ---------------- row inverse norms: x [rows][1024] ----------------
__global__ __launch_bounds__(256) void k_invnorm(const float* __restrict__ x,
                                                 float* __restrict__ out, int rows) {
    int wid = threadIdx.x >> 6;
    int lane = threadIdx.x & 63;
    int row = blockIdx.x * 4 + wid;
    if (row >= rows) return;
    const float* xr = x + (size_t)row * 1024;
    float s = 0.0f;
#pragma unroll
    for (int i = 0; i < 4; i++) {
        float4 v = *(const float4*)&xr[i * 256 + lane * 4];
        s += v.x * v.x + v.y * v.y + v.z * v.z + v.w * v.w;
    }
#pragma unroll
    for (int off = 32; off > 0; off >>= 1) s += __shfl_xor(s, off);
    if (lane == 0) out[row] = 1.0f / fmaxf(sqrtf(s), 1e-12f);
}

// ---------------- sim[i][j] = dot(v_g[i], t_g[j]) * iv[i]*it[j] / TEMP ----------------
__global__ __launch_bounds__(128) void k_sim(const float* __restrict__ vg,
                                             const float* __restrict__ tg,
                                             const float* __restrict__ ivg,
                                             const float* __restrict__ itg,
                                             float* __restrict__ sim) {
    int i = blockIdx.x, j = threadIdx.x;
    const float* vr = vg + (size_t)i * 1024;
    const float* tr = tg + (size_t)j * 1024;
    float acc = 0.0f;
    for (int k = 0; k < 1024; k += 4) {
        float4 a = *(const float4*)&vr[k];
        float4 b = *(const float4*)&tr[k];
        acc += a.x * b.x + a.y * b.y + a.z * b.z + a.w * b.w;
    }
    sim[i * 128 + j] = acc * ivg[i] * itg[j] / TEMPERATURE;
}

// ---------------- L_global from sim (single block, 128 threads) ----------------
__global__ __launch_bounds__(128) void k_global(const float* __restrict__ sim,
                                                float* __restrict__ acc) {
    __shared__ float red[128];
    int t = threadIdx.x;
    float m = -3e38f, m2 = -3e38f;
    for (int j = 0; j < 128; j++) {
        m = fmaxf(m, sim[t * 128 + j]);
        m2 = fmaxf(m2, sim[j * 128 + t]);
    }
    float s = 0.0f, s2 = 0.0f;
    for (int j = 0; j < 128; j++) {
        s += expf(sim[t * 128 + j] - m);
        s2 += expf(sim[j * 128 + t] - m2);
    }
    float contrib = 2.0f * sim[t * 128 + t] - (m + logf(s)) - (m2 + logf(s2));
    red[t] = contrib;
    __syncthreads();
    for (int o = 64; o > 0; o >>= 1) {
        if (t < o) red[t] += red[t + o];
        __syncthreads();
    }
    if (t == 0) acc[0] = -red[0] / 256.0f;   // 0.5*(mean+mean), negated
}

// ---------------- cost[b][n][m] = 1 - cos(V[b,n], T[b,m]) ----------------
// 64x64 output tile per block, 4x4 register tile per thread, K-chunks of 16 in LDS.
__global__ __launch_bounds__(256) void k_cost(const float* __restrict__ V,
                                              const float* __restrict__ T,
                                              const float* __restrict__ ivv,
                                              const float* __restrict__ ivt,
                                              float* __restrict__ cost) {
    __shared__ float As[16][68];  // [k][row], padded
    __shared__ float Bs[16][68];
    int b = blockIdx.x >> 2;
    int tile = blockIdx.x & 3;
    int n0 = (tile >> 1) * 64, m0 = (tile & 1) * 64;
    int t = threadIdx.x;
    int lr = t >> 2;   // 0..63 (tile row)
    int lq = t & 3;    // 0..3  (k quarter)
    int tm = t >> 4;   // 0..15
    int tn = t & 15;   // 0..15
    const float* Vb = V + (size_t)b * 128 * 1024;
    const float* Tb = T + (size_t)b * 128 * 1024;
    float acc[4][4];
#pragma unroll
    for (int i = 0; i < 4; i++)
#pragma unroll
        for (int j = 0; j < 4; j++) acc[i][j] = 0.0f;

    for (int k0 = 0; k0 < 1024; k0 += 16) {
        float4 av = *(const float4*)&Vb[(size_t)(n0 + lr) * 1024 + k0 + lq * 4];
        float4 bv = *(const float4*)&Tb[(size_t)(m0 + lr) * 1024 + k0 + lq * 4];
        __syncthreads();
        As[lq * 4 + 0][lr] = av.x; As[lq * 4 + 1][lr] = av.y;
        As[lq * 4 + 2][lr] = av.z; As[lq * 4 + 3][lr] = av.w;
        Bs[lq * 4 + 0][lr] = bv.x; Bs[lq * 4 + 1][lr] = bv.y;
        Bs[lq * 4 + 2][lr] = bv.z; Bs[lq * 4 + 3][lr] = bv.w;
        __syncthreads();
#pragma unroll
        for (int k = 0; k < 16; k++) {
            float4 a = *(const float4*)&As[k][tm * 4];
            float4 q = *(const float4*)&Bs[k][tn * 4];
            acc[0][0] += a.x * q.x; acc[0][1] += a.x * q.y; acc[0][2] += a.x * q.z; acc[0][3] += a.x * q.w;
            acc[1][0] += a.y * q.x; acc[1][1] += a.y * q.y; acc[1][2] += a.y * q.z; acc[1][3] += a.y * q.w;
            acc[2][0] += a.z * q.x; acc[2][1] += a.z * q.y; acc[2][2] += a.z * q.z; acc[2][3] += a.z * q.w;
            acc[3][0] += a.w * q.x; acc[3][1] += a.w * q.y; acc[3][2] += a.w * q.z; acc[3][3] += a.w * q.w;
        }
    }
    int nb = n0 + tm * 4, mb = m0 + tn * 4;
    float im[4];
#pragma unroll
    for (int j = 0; j < 4; j++) im[j] = ivt[b * 128 + mb + j];
#pragma unroll
    for (int i = 0; i < 4; i++) {
        float in_ = ivv[b * 128 + nb + i];
        float4 o;
        o.x = 1.0f - acc[i][0] * in_ * im[0];
        o.y = 1.0f - acc[i][1] * in_ * im[1];
        o.z = 1.0f - acc[i][2] * in_ * im[2];
        o.w = 1.0f - acc[i][3] * in_ * im[3];
        *(float4*)&cost[((size_t)b * 128 + nb + i) * 128 + mb] = o;
    }
}

// ---------------- fast wave-uniform lane read (VALU readlane, not ds_bpermute) ----
__device__ __forceinline__ int rdlane_i(int v, int l) {
    return __builtin_amdgcn_readlane(v, l);
}
__device__ __forceinline__ float rdlane_f(float v, int l) {
    return __int_as_float(__builtin_amdgcn_readlane(__float_as_int(v), l));
}

// ---------------- DPP full-wave min (result valid in lane 63) ----------------
// update_dpp(old=INF, src, ctrl, 0xF, 0xF, false): invalid source lanes get INF.
#define HUNG_INF 3.0e38f
__device__ __forceinline__ float dpp_wave_min(float x) {
    const int INFB = __float_as_int(HUNG_INF);
    int o;
    o = __builtin_amdgcn_update_dpp(INFB, __float_as_int(x), 0x111, 0xF, 0xF, false); // row_shr:1
    x = fminf(x, __int_as_float(o));
    o = __builtin_amdgcn_update_dpp(INFB, __float_as_int(x), 0x112, 0xF, 0xF, false); // row_shr:2
    x = fminf(x, __int_as_float(o));
    o = __builtin_amdgcn_update_dpp(INFB, __float_as_int(x), 0x114, 0xF, 0xF, false); // row_shr:4
    x = fminf(x, __int_as_float(o));
    o = __builtin_amdgcn_update_dpp(INFB, __float_as_int(x), 0x118, 0xF, 0xF, false); // row_shr:8
    x = fminf(x, __int_as_float(o));
    o = __builtin_amdgcn_update_dpp(INFB, __float_as_int(x), 0x142, 0xF, 0xF, false); // row_bcast:15
    x = fminf(x, __int_as_float(o));
    o = __builtin_amdgcn_update_dpp(INFB, __float_as_int(x), 0x143, 0xF, 0xF, false); // row_bcast:31
    x = fminf(x, __int_as_float(o));
    return x;
}

// ---------------- Hungarian (JV) — one wave per batch problem ----------------
// Lane l owns columns l and l+64, and rows l and l+64. All JV state in registers;
// cost matrix in LDS; wave-uniform control flow.
// Latency-chain engineering: every cross-lane lookup uses v_readlane (uniform
// index, VALU pipe); the argmin uses a DPP min tree + ballot for the index —
// no ds_bpermute anywhere in the hot loop.
__global__ __launch_bounds__(64) void k_hungarian(const float* __restrict__ cost,
                                                  int* __restrict__ cols) {
    extern __shared__ float C[];  // 128*128 floats = 64 KB
    int b = blockIdx.x;
    int lane = threadIdx.x;
    for (int i = lane * 4; i < 16384; i += 256)
        *(float4*)&C[i] = *(const float4*)&cost[(size_t)b * 16384 + i];
    __syncthreads();

    const float INF = HUNG_INF;
    float v0 = 0.0f, v1 = 0.0f, u0 = 0.0f, u1 = 0.0f;
    int p0 = -1, p1 = -1;

    for (int i = 0; i < 128; i++) {
        float minv0 = INF, minv1 = INF;
        int way0 = 128, way1 = 128;
        bool used0 = false, used1 = false, intree0 = false, intree1 = false;
        if (lane == (i & 63)) { if (i < 64) intree0 = true; else intree1 = true; }
        int j0 = 128;  // virtual column
        int guard = 0;
        while (true) {
            int i0;
            if (j0 == 128) {
                i0 = i;
            } else {
                int jl = j0 & 63;
                i0 = rdlane_i((j0 >= 64) ? p1 : p0, jl);
                if (lane == jl) { if (j0 >= 64) used1 = true; else used0 = true; }
                if (lane == (i0 & 63)) { if (i0 < 64) intree0 = true; else intree1 = true; }
            }
            float ui0 = rdlane_f((i0 >= 64) ? u1 : u0, i0 & 63);
            float c0 = C[i0 * 128 + lane];
            float c1 = C[i0 * 128 + 64 + lane];
            float cur0 = c0 - ui0 - v0;
            float cur1 = c1 - ui0 - v1;
            if (!used0 && cur0 < minv0) { minv0 = cur0; way0 = j0; }
            if (!used1 && cur1 < minv1) { minv1 = cur1; way1 = j0; }
            float cand0 = used0 ? INF : minv0;
            float cand1 = used1 ? INF : minv1;
            // wave-wide argmin: DPP value min-reduce, then ballot for lowest index.
            float m = dpp_wave_min(fminf(cand0, cand1));
            float delta = rdlane_f(m, 63);
            unsigned long long m0 = __ballot(cand0 == delta);
            unsigned long long m1 = __ballot(cand1 == delta);
            int j1 = m0 ? (__ffsll((long long)m0) - 1) : (64 + __ffsll((long long)m1) - 1);
            if (used0) v0 -= delta; else minv0 -= delta;
            if (used1) v1 -= delta; else minv1 -= delta;
            if (intree0) u0 += delta;
            if (intree1) u1 += delta;
            j0 = j1;
            int pj = rdlane_i((j0 >= 64) ? p1 : p0, j0 & 63);
            if (pj < 0 || ++guard > 200) break;
        }
        // augment along alternating path
        while (j0 != 128) {
            int w = rdlane_i((j0 >= 64) ? way1 : way0, j0 & 63);
            int pw = (w == 128) ? i : rdlane_i((w >= 64) ? p1 : p0, w & 63);
            if (lane == (j0 & 63)) { if (j0 >= 64) p1 = pw; else p0 = pw; }
            j0 = w;
        }
    }
    // p[j] = row matched to column j  ->  cols[row] = j
    cols[b * 128 + p0] = lane;
    cols[b * 128 + p1] = lane + 64;
}

// ---------------- node MSE: one block per (b,n) row ----------------
__global__ __launch_bounds__(256) void k_node(const float* __restrict__ V,
                                              const float* __restrict__ T,
                                              const int* __restrict__ cols,
                                              float* __restrict__ acc) {
    int bn = blockIdx.x;
    int b = bn >> 7, n = bn & 127;
    int c = cols[bn];
    const float* vr = V + ((size_t)b * 128 + n) * 1024;
    const float* tr = T + ((size_t)b * 128 + c) * 1024;
    int t = threadIdx.x;
    float4 a = *(const float4*)&vr[t * 4];
    float4 bb = *(const float4*)&tr[t * 4];
    float dx = a.x - bb.x, dy = a.y - bb.y, dz = a.z - bb.z, dw = a.w - bb.w;
    float s = dx * dx + dy * dy + dz * dz + dw * dw;
#pragma unroll
    for (int off = 32; off > 0; off >>= 1) s += __shfl_xor(s, off);
    __shared__ float wsum[4];
    if ((t & 63) == 0) wsum[t >> 6] = s;
    __syncthreads();
    if (t == 0) atomicAdd(&acc[1], wsum[0] + wsum[1] + wsum[2] + wsum[3]);
}

// ---------------- graph MSE ----------------
__global__ __launch_bounds__(256) void k_graph(const float* __restrict__ Av,
                                               const float* __restrict__ At,
                                               float* __restrict__ acc) {
    size_t idx = ((size_t)blockIdx.x * 256 + threadIdx.x) * 4;
    float4 a = *(const float4*)&Av[idx];
    float4 bb = *(const float4*)&At[idx];
    float dx = a.x - bb.x, dy = a.y - bb.y, dz = a.z - bb.z, dw = a.w - bb.w;
    float s = dx * dx + dy * dy + dz * dz + dw * dw;
#pragma unroll
    for (int off = 32; off > 0; off >>= 1) s += __shfl_xor(s, off);
    __shared__ float wsum[4];
    int t = threadIdx.x;
    if ((t & 63) == 0) wsum[t >> 6] = s;
    __syncthreads();
    if (t == 0) atomicAdd(&acc[2], wsum[0] + wsum[1] + wsum[2] + wsum[3]);
}

// ---------------- finalize ----------------
__global__ void k_final(const float* __restrict__ acc, float* __restrict__ out) {
    float lg = acc[0];
    float ln = acc[1] / 16777216.0f;   // 128*128*1024
    float lgr = acc[2] / 2097152.0f;   // 128*128*128
    out[0] = lg + ln + lgr;
    out[1] = lg;
    out[2] = ln;
    out[3] = lgr;
}

extern "C" void kernel_launch(void* const* d_in, const int* in_sizes, int n_in,
                              void* d_out, int out_size, void* d_ws, size_t ws_size,
                              hipStream_t stream) {
    const float* vg = (const float*)d_in[0];
    const float* tg = (const float*)d_in[1];
    const float* V  = (const float*)d_in[2];
    const float* T  = (const float*)d_in[3];
    const float* Av = (const float*)d_in[4];
    const float* At = (const float*)d_in[5];
    float* out = (float*)d_out;
    float* ws = (float*)d_ws;

    float* cost = ws + WS_COST;
    float* sim  = ws + WS_SIM;
    float* ivg  = ws + WS_IVG;
    float* itg  = ws + WS_ITG;
    float* ivv  = ws + WS_IVV;
    float* ivt  = ws + WS_IVT;
    int*   cols = (int*)(ws + WS_COLS);
    float* acc  = ws + WS_ACC;

    k_init<<<1, 16, 0, stream>>>(acc);

    k_invnorm<<<32, 256, 0, stream>>>(vg, ivg, 128);
    k_invnorm<<<32, 256, 0, stream>>>(tg, itg, 128);
    k_invnorm<<<4096, 256, 0, stream>>>(V, ivv, 16384);
    k_invnorm<<<4096, 256, 0, stream>>>(T, ivt, 16384);

    k_sim<<<128, 128, 0, stream>>>(vg, tg, ivg, itg, sim);
    k_global<<<1, 128, 0, stream>>>(sim, acc);

    k_cost<<<512, 256, 0, stream>>>(V, T, ivv, ivt, cost);
    k_hungarian<<<128, 64, 65536, stream>>>(cost, cols);

    k_node<<<16384, 256, 0, stream>>>(V, T, cols, acc);
    k_graph<<<2048, 256, 0, stream>>>(Av, At, acc);

    k_final<<<1, 1, 0, stream>>>(acc, out);
}